// Round 1
// baseline (752.330 us; speedup 1.0000x reference)
//
#include <hip/hip_runtime.h>

// Dims fixed by setup_inputs(): B=4, C=64, H=W=64 -> T=4096, HEADS=8, dh=8, k=T/4=1024
#define T_DIM 4096
#define KD    1024
#define SCALE 0.35355339059327373f   // 8^-0.5

// ---------------------------------------------------------------------------
// K1: qkv = xf @ Wqkv, scattered into Q [B,h,T,8] and KV [T, 512]
//     KV col = (b*8+h)*16 + sel*8 + d   (sel: 0=K, 1=V)
//     qkv col decomposition (reference reshape): col = d*24 + k3*8 + h
// ---------------------------------------------------------------------------
__global__ __launch_bounds__(256) void k_qkv(const float* __restrict__ x,
                                             const float* __restrict__ Wqkv,
                                             float* __restrict__ Q,
                                             float* __restrict__ KV) {
  const int g  = blockIdx.x;                 // col group 0..3 (48 cols each)
  const int tt = blockIdx.y;                 // 0..15
  const int b  = blockIdx.z;                 // 0..3
  const int t  = tt * 256 + threadIdx.x;     // token (lane-consecutive)
  const int col0 = g * 48;

  float acc[48];
#pragma unroll
  for (int j = 0; j < 48; ++j) acc[j] = 0.f;

  const float* xb = x + (size_t)b * 64 * T_DIM + t;
  for (int c = 0; c < 64; ++c) {
    float xv = xb[(size_t)c * T_DIM];                 // coalesced vector load
    const float* wr = Wqkv + c * 192 + col0;          // uniform -> s_load
#pragma unroll
    for (int j = 0; j < 48; ++j) acc[j] += xv * wr[j];
  }

#pragma unroll
  for (int j = 0; j < 48; ++j) {
    const int col = col0 + j;                 // compile-time per j
    const int d = col / 24, r = col % 24, k3 = r / 8, h = r % 8;
    if (k3 == 0)
      Q[(((size_t)b * 8 + h) * T_DIM + t) * 8 + d] = acc[j];
    else
      KV[(size_t)t * 512 + ((b * 8 + h) * 16 + (k3 - 1) * 8 + d)] = acc[j];
  }
}

// ---------------------------------------------------------------------------
// K2: low-rank projection GEMM: partial[s][bh][k][ch] += E^T @ KV over t-slice
//     lanes span k (coalesced E reads); KV row is wave-uniform -> s_load
// ---------------------------------------------------------------------------
__global__ __launch_bounds__(256) void k_proj(const float* __restrict__ E,
                                              const float* __restrict__ KV,
                                              float* __restrict__ partial) {
  const int kk   = blockIdx.x * 256 + threadIdx.x;  // k index 0..1023
  const int col0 = blockIdx.y * 64;                 // 0..511 in steps of 64
  const int s    = blockIdx.z;                      // t-split 0..7

  float acc[64];
#pragma unroll
  for (int j = 0; j < 64; ++j) acc[j] = 0.f;

  const int t0 = s * 512;
  for (int t = t0; t < t0 + 512; ++t) {
    float e = E[(size_t)t * KD + kk];                // coalesced
    const float* kvr = KV + (size_t)t * 512 + col0;  // uniform -> s_load
#pragma unroll
    for (int j = 0; j < 64; ++j) acc[j] += e * kvr[j];
  }

  float* pb = partial + (size_t)s * (32 * KD * 16);
#pragma unroll
  for (int j4 = 0; j4 < 16; ++j4) {
    const int col = col0 + j4 * 4;
    const int bh = col >> 4, ch = col & 15;          // 4 consecutive ch in one bh
    float4 v = make_float4(acc[j4*4], acc[j4*4+1], acc[j4*4+2], acc[j4*4+3]);
    *(float4*)(pb + (size_t)bh * (KD * 16) + (size_t)kk * 16 + ch) = v;
  }
}

// ---------------------------------------------------------------------------
// K2b: sum the 8 t-split partials -> KVP [bh][k][16] (kp[0:8] | vp[8:16])
// ---------------------------------------------------------------------------
__global__ __launch_bounds__(256) void k_reduce(const float* __restrict__ partial,
                                               float* __restrict__ KVP) {
  const size_t i = ((size_t)blockIdx.x * 256 + threadIdx.x) * 4;  // 524288 floats total
  float4 a = make_float4(0.f, 0.f, 0.f, 0.f);
#pragma unroll
  for (int s = 0; s < 8; ++s) {
    float4 v = *(const float4*)(partial + (size_t)s * 524288 + i);
    a.x += v.x; a.y += v.y; a.z += v.z; a.w += v.w;
  }
  *(float4*)(KVP + i) = a;
}

// ---------------------------------------------------------------------------
// K3: attention. One thread = one query row. KVP rows are wave-uniform ->
//     s_load_dwordx16 (kp|vp interleaved, 64B/row). Fixed-shift softmax.
// ---------------------------------------------------------------------------
__global__ __launch_bounds__(256) void k_attn(const float* __restrict__ Q,
                                              const float* __restrict__ KVP,
                                              float* __restrict__ O) {
  const int bh = blockIdx.x;                        // 0..31
  const int i  = blockIdx.y * 256 + threadIdx.x;    // query row

  const float* qp = Q + ((size_t)bh * T_DIM + i) * 8;
  float ql[8];
#pragma unroll
  for (int d = 0; d < 8; ++d) ql[d] = qp[d] * SCALE;

  const float* kv = KVP + (size_t)bh * (KD * 16);
  float acc[8];
#pragma unroll
  for (int d = 0; d < 8; ++d) acc[d] = 0.f;
  float l = 0.f;

#pragma unroll 4
  for (int j = 0; j < KD; ++j) {
    const float* row = kv + j * 16;                 // uniform -> s_load x16
    float sc = 0.f;
#pragma unroll
    for (int d = 0; d < 8; ++d) sc += ql[d] * row[d];
    float p = __expf(sc - 12.0f);                   // shift-invariant softmax
    l += p;
#pragma unroll
    for (int d = 0; d < 8; ++d) acc[d] += p * row[8 + d];
  }

  const float inv = 1.0f / l;
  const int b = bh >> 3, h = bh & 7;
  float* op = O + ((size_t)b * T_DIM + i) * 64 + h * 8;   // O[b][t][c], c=h*8+d
#pragma unroll
  for (int d = 0; d < 8; ++d) op[d] = acc[d] * inv;
}

// ---------------------------------------------------------------------------
// K4: out[b][c][t] = (O[b][t][:] @ W0)[c]   (W0 rows wave-uniform -> s_load)
// ---------------------------------------------------------------------------
__global__ __launch_bounds__(256) void k_out(const float* __restrict__ O,
                                             const float* __restrict__ W0,
                                             float* __restrict__ out) {
  const int cg = blockIdx.x;                 // 0..1 (32 out cols each)
  const int tt = blockIdx.y;                 // 0..15
  const int b  = blockIdx.z;                 // 0..3
  const int t  = tt * 256 + threadIdx.x;
  const int col0 = cg * 32;

  float acc[32];
#pragma unroll
  for (int j = 0; j < 32; ++j) acc[j] = 0.f;

  const float* orow = O + ((size_t)b * T_DIM + t) * 64;
  for (int c0 = 0; c0 < 64; c0 += 16) {
    float ov[16];
#pragma unroll
    for (int u4 = 0; u4 < 4; ++u4) {
      float4 v = *(const float4*)(orow + c0 + u4 * 4);
      ov[u4*4] = v.x; ov[u4*4+1] = v.y; ov[u4*4+2] = v.z; ov[u4*4+3] = v.w;
    }
#pragma unroll
    for (int u = 0; u < 16; ++u) {
      const float* wr = W0 + (c0 + u) * 64 + col0;   // uniform -> s_load
#pragma unroll
      for (int j = 0; j < 32; ++j) acc[j] += ov[u] * wr[j];
    }
  }
#pragma unroll
  for (int j = 0; j < 32; ++j)
    out[((size_t)b * 64 + col0 + j) * T_DIM + t] = acc[j];   // coalesced
}

// ---------------------------------------------------------------------------
extern "C" void kernel_launch(void* const* d_in, const int* in_sizes, int n_in,
                              void* d_out, int out_size, void* d_ws, size_t ws_size,
                              hipStream_t stream) {
  const float* x    = (const float*)d_in[0];
  // d_in[1..4] = conv_w, conv_b, ln_g, ln_b : dead code in the reference
  const float* Wqkv = (const float*)d_in[5];
  const float* W0   = (const float*)d_in[6];
  const float* E    = (const float*)d_in[7];
  float* out = (float*)d_out;

  float* Q       = (float*)d_ws;            // 1,048,576 floats (4 MB)
  float* KV      = Q + 1048576;             // 2,097,152 floats (8 MB)
  float* partial = KV + 2097152;            // 4,194,304 floats (16 MB)
  float* KVP     = partial + 4194304;       //   524,288 floats (2 MB)
  float* O       = KVP + 524288;            // 1,048,576 floats (4 MB)  total 34 MB

  k_qkv   <<<dim3(4, 16, 4), 256, 0, stream>>>(x, Wqkv, Q, KV);
  k_proj  <<<dim3(4, 8, 8),  256, 0, stream>>>(E, KV, partial);
  k_reduce<<<dim3(512),      256, 0, stream>>>(partial, KVP);
  k_attn  <<<dim3(32, 16),   256, 0, stream>>>(Q, KVP, O);
  k_out   <<<dim3(2, 16, 4), 256, 0, stream>>>(O, W0, out);
}

// Round 2
// 227.657 us; speedup vs baseline: 3.3047x; 3.3047x over previous
//
#include <hip/hip_runtime.h>

// Dims fixed by setup_inputs(): B=4, C=64, H=W=64 -> T=4096, HEADS=8, dh=8, k=T/4=1024
#define T_DIM 4096
#define KD    1024
#define SCALE 0.35355339059327373f   // 8^-0.5

typedef __attribute__((ext_vector_type(8))) short bf16x8;
typedef __attribute__((ext_vector_type(4))) float f32x4;

__device__ inline unsigned short f2bf(float f) {   // RNE fp32 -> bf16
  unsigned u = __float_as_uint(f);
  unsigned r = u + 0x7fffu + ((u >> 16) & 1u);
  return (unsigned short)(r >> 16);
}

// ---------------------------------------------------------------------------
// K1: qkv = xf @ Wqkv. Group g = one d (since cols [24g,24g+24) share d=g).
//     j 0..7  -> Q  (h=j)  : Q[bh][d=g][t]  fp32, coalesced in t
//     j 8..15 -> K  (h=j-8): KVt[col][t] bf16, col=(b*8+h)*16 + g
//     j 16..23-> V         : col=(b*8+h)*16 + 8 + g
// ---------------------------------------------------------------------------
__global__ __launch_bounds__(256) void k_qkv(const float* __restrict__ x,
                                             const float* __restrict__ Wqkv,
                                             float* __restrict__ Q,
                                             unsigned short* __restrict__ KVt) {
  const int g  = blockIdx.x;                 // 0..7 (= d index)
  const int tt = blockIdx.y;                 // 0..15
  const int b  = blockIdx.z;                 // 0..3
  const int t  = tt * 256 + threadIdx.x;
  const int col0 = g * 24;

  float acc[24];
#pragma unroll
  for (int j = 0; j < 24; ++j) acc[j] = 0.f;

  const float* xb = x + (size_t)b * 64 * T_DIM + t;
#pragma unroll 2
  for (int c = 0; c < 64; ++c) {
    float xv = xb[(size_t)c * T_DIM];               // coalesced
    const float* wr = Wqkv + c * 192 + col0;        // wave-uniform -> s_load
#pragma unroll
    for (int j = 0; j < 24; ++j) acc[j] += xv * wr[j];
  }

#pragma unroll
  for (int h = 0; h < 8; ++h)
    Q[(((size_t)(b * 8 + h)) * 8 + g) * T_DIM + t] = acc[h];
#pragma unroll
  for (int h = 0; h < 8; ++h) {
    const int colK = (b * 8 + h) * 16 + g;
    const int colV = colK + 8;
    KVt[(size_t)colK * T_DIM + t] = f2bf(acc[8 + h]);
    KVt[(size_t)colV * T_DIM + t] = f2bf(acc[16 + h]);
  }
}

// ---------------------------------------------------------------------------
// K1b: Et = bf16(E^T): E fp32 [4096 t][1024 k] -> Et bf16 [1024 k][4096 t]
// ---------------------------------------------------------------------------
__global__ __launch_bounds__(256) void k_et(const float* __restrict__ E,
                                            unsigned short* __restrict__ Et) {
  __shared__ float Ts[64 * 65];            // [k-in-tile][t-in-tile], pad 65
  const int t0 = blockIdx.x * 64;          // 0..4032
  const int k0 = blockIdx.y * 64;          // 0..960
  const int tid = threadIdx.x;

  const int c = tid & 63;                  // k within tile
#pragma unroll
  for (int ii = 0; ii < 16; ++ii) {
    const int r = (tid >> 6) * 16 + ii;    // t within tile
    Ts[c * 65 + r] = E[(size_t)(t0 + r) * KD + k0 + c];   // coalesced read
  }
  __syncthreads();

  const int p = tid & 31;                  // t-pair index
#pragma unroll
  for (int ii = 0; ii < 8; ++ii) {
    const int kk = (tid >> 5) * 8 + ii;
    unsigned short lo = f2bf(Ts[kk * 65 + 2 * p]);
    unsigned short hi = f2bf(Ts[kk * 65 + 2 * p + 1]);
    unsigned v = (unsigned)lo | ((unsigned)hi << 16);
    *(unsigned*)(Et + (size_t)(k0 + kk) * T_DIM + t0 + 2 * p) = v;  // coalesced
  }
}

// ---------------------------------------------------------------------------
// K2: MFMA GEMM: partial[s][m][n] = sum_t Et[m][t] * KVt[n][t]
//     64x64 tile, BK=64, 4 waves each computing a 32x32 quadrant (2x2 MFMAs)
// ---------------------------------------------------------------------------
__global__ __launch_bounds__(256) void k_proj_mfma(const unsigned short* __restrict__ Et,
                                                   const unsigned short* __restrict__ KVt,
                                                   float* __restrict__ partial) {
  __shared__ unsigned short As[64 * 72];   // [m][t], pitch 72 bf16 (conflict-free)
  __shared__ unsigned short Bs[64 * 72];   // [n][t]
  const int m0 = blockIdx.x * 64;
  const int n0 = blockIdx.y * 64;
  const int s  = blockIdx.z;               // t-split 0..3
  const int tid = threadIdx.x;
  const int lane = tid & 63;
  const int w = tid >> 6;
  const int mw = (w & 1) * 32, nw = (w >> 1) * 32;

  f32x4 acc[2][2] = {};
  const int r0 = tid >> 3, o0 = tid & 7;   // staging: row, 16B-chunk

  for (int tb = 0; tb < 1024; tb += 64) {
    const int tbase = s * 1024 + tb;
    bf16x8 va  = *(const bf16x8*)(Et  + (size_t)(m0 + r0)      * T_DIM + tbase + o0 * 8);
    bf16x8 va2 = *(const bf16x8*)(Et  + (size_t)(m0 + r0 + 32) * T_DIM + tbase + o0 * 8);
    bf16x8 vb  = *(const bf16x8*)(KVt + (size_t)(n0 + r0)      * T_DIM + tbase + o0 * 8);
    bf16x8 vb2 = *(const bf16x8*)(KVt + (size_t)(n0 + r0 + 32) * T_DIM + tbase + o0 * 8);
    __syncthreads();                       // previous-iter reads done
    *(bf16x8*)(As + r0 * 72 + o0 * 8)        = va;
    *(bf16x8*)(As + (r0 + 32) * 72 + o0 * 8) = va2;
    *(bf16x8*)(Bs + r0 * 72 + o0 * 8)        = vb;
    *(bf16x8*)(Bs + (r0 + 32) * 72 + o0 * 8) = vb2;
    __syncthreads();

#pragma unroll
    for (int ks = 0; ks < 2; ++ks) {
      const int ko = ks * 32 + (lane >> 4) * 8;
      bf16x8 a0 = *(const bf16x8*)(As + (mw +      (lane & 15)) * 72 + ko);
      bf16x8 a1 = *(const bf16x8*)(As + (mw + 16 + (lane & 15)) * 72 + ko);
      bf16x8 b0 = *(const bf16x8*)(Bs + (nw +      (lane & 15)) * 72 + ko);
      bf16x8 b1 = *(const bf16x8*)(Bs + (nw + 16 + (lane & 15)) * 72 + ko);
      acc[0][0] = __builtin_amdgcn_mfma_f32_16x16x32_bf16(a0, b0, acc[0][0], 0, 0, 0);
      acc[0][1] = __builtin_amdgcn_mfma_f32_16x16x32_bf16(a0, b1, acc[0][1], 0, 0, 0);
      acc[1][0] = __builtin_amdgcn_mfma_f32_16x16x32_bf16(a1, b0, acc[1][0], 0, 0, 0);
      acc[1][1] = __builtin_amdgcn_mfma_f32_16x16x32_bf16(a1, b1, acc[1][1], 0, 0, 0);
    }
  }

  // C/D layout: col = lane&15, row = (lane>>4)*4 + reg  [verified m89]
  float* pb = partial + (size_t)s * (KD * 512);
#pragma unroll
  for (int rr = 0; rr < 2; ++rr)
#pragma unroll
    for (int cc = 0; cc < 2; ++cc) {
      const int mrow = m0 + mw + rr * 16 + (lane >> 4) * 4;
      const int ncol = n0 + nw + cc * 16 + (lane & 15);
#pragma unroll
      for (int reg = 0; reg < 4; ++reg)
        pb[(size_t)(mrow + reg) * 512 + ncol] = acc[rr][cc][reg];
    }
}

// ---------------------------------------------------------------------------
// K2b: KVP[bh][k][16] = sum_s partial[s][k][bh*16+ch]
// ---------------------------------------------------------------------------
__global__ __launch_bounds__(256) void k_reduce(const float* __restrict__ partial,
                                                float* __restrict__ KVP) {
  const size_t o = ((size_t)blockIdx.x * 256 + threadIdx.x) * 4;  // 524288 floats
  const int ch0 = (int)(o & 15);
  const int k   = (int)((o >> 4) & 1023);
  const int bh  = (int)(o >> 14);
  const size_t src = (size_t)k * 512 + bh * 16 + ch0;
  float4 a = make_float4(0.f, 0.f, 0.f, 0.f);
#pragma unroll
  for (int s = 0; s < 4; ++s) {
    float4 v = *(const float4*)(partial + (size_t)s * (KD * 512) + src);
    a.x += v.x; a.y += v.y; a.z += v.z; a.w += v.w;
  }
  *(float4*)(KVP + o) = a;
}

// ---------------------------------------------------------------------------
// K3: attention. One thread = one query row; KVP rows wave-uniform -> s_load.
// ---------------------------------------------------------------------------
__global__ __launch_bounds__(256) void k_attn(const float* __restrict__ Q,
                                              const float* __restrict__ KVP,
                                              float* __restrict__ O) {
  const int bh = blockIdx.x;                        // 0..31
  const int i  = blockIdx.y * 256 + threadIdx.x;    // query row

  float ql[8];
#pragma unroll
  for (int d = 0; d < 8; ++d)
    ql[d] = Q[(((size_t)bh) * 8 + d) * T_DIM + i] * SCALE;   // coalesced per d

  const float* kv = KVP + (size_t)bh * (KD * 16);
  float acc[8];
#pragma unroll
  for (int d = 0; d < 8; ++d) acc[d] = 0.f;
  float l = 0.f;

#pragma unroll 4
  for (int j = 0; j < KD; ++j) {
    const float* row = kv + j * 16;                 // uniform -> s_load x16
    float sc = 0.f;
#pragma unroll
    for (int d = 0; d < 8; ++d) sc += ql[d] * row[d];
    float p = __expf(sc - 12.0f);                   // shift-invariant softmax
    l += p;
#pragma unroll
    for (int d = 0; d < 8; ++d) acc[d] += p * row[8 + d];
  }

  const float inv = 1.0f / l;
  const int b = bh >> 3, h = bh & 7;
  float* op = O + ((size_t)b * T_DIM + i) * 64 + h * 8;   // O[b][t][c], c=h*8+d
#pragma unroll
  for (int d = 0; d < 8; ++d) op[d] = acc[d] * inv;
}

// ---------------------------------------------------------------------------
// K4: out[b][c][t] = (O[b][t][:] @ W0)[c]
// ---------------------------------------------------------------------------
__global__ __launch_bounds__(256) void k_out(const float* __restrict__ O,
                                             const float* __restrict__ W0,
                                             float* __restrict__ out) {
  const int cg = blockIdx.x;                 // 0..1
  const int tt = blockIdx.y;                 // 0..15
  const int b  = blockIdx.z;                 // 0..3
  const int t  = tt * 256 + threadIdx.x;
  const int col0 = cg * 32;

  float acc[32];
#pragma unroll
  for (int j = 0; j < 32; ++j) acc[j] = 0.f;

  const float* orow = O + ((size_t)b * T_DIM + t) * 64;
  for (int c0 = 0; c0 < 64; c0 += 16) {
    float ov[16];
#pragma unroll
    for (int u4 = 0; u4 < 4; ++u4) {
      float4 v = *(const float4*)(orow + c0 + u4 * 4);
      ov[u4 * 4] = v.x; ov[u4 * 4 + 1] = v.y; ov[u4 * 4 + 2] = v.z; ov[u4 * 4 + 3] = v.w;
    }
#pragma unroll
    for (int u = 0; u < 16; ++u) {
      const float* wr = W0 + (c0 + u) * 64 + col0;   // uniform -> s_load
#pragma unroll
      for (int j = 0; j < 32; ++j) acc[j] += ov[u] * wr[j];
    }
  }
#pragma unroll
  for (int j = 0; j < 32; ++j)
    out[((size_t)b * 64 + col0 + j) * T_DIM + t] = acc[j];   // coalesced
}

// ---------------------------------------------------------------------------
extern "C" void kernel_launch(void* const* d_in, const int* in_sizes, int n_in,
                              void* d_out, int out_size, void* d_ws, size_t ws_size,
                              hipStream_t stream) {
  const float* x    = (const float*)d_in[0];
  // d_in[1..4] = conv_w, conv_b, ln_g, ln_b : dead code in the reference
  const float* Wqkv = (const float*)d_in[5];
  const float* W0   = (const float*)d_in[6];
  const float* E    = (const float*)d_in[7];
  float* out = (float*)d_out;

  // workspace layout (30 MB total)
  float* Q       = (float*)d_ws;                    // 1,048,576 f (4 MB)
  float* O       = Q + 1048576;                     // 1,048,576 f (4 MB)
  float* KVP     = O + 1048576;                     //   524,288 f (2 MB)
  float* partial = KVP + 524288;                    // 2,097,152 f (8 MB)
  unsigned short* KVt = (unsigned short*)(partial + 2097152);  // 2,097,152 bf16 (4 MB)
  unsigned short* Et  = KVt + 2097152;              // 4,194,304 bf16 (8 MB)

  k_qkv      <<<dim3(8, 16, 4), 256, 0, stream>>>(x, Wqkv, Q, KVt);
  k_et       <<<dim3(64, 16),   256, 0, stream>>>(E, Et);
  k_proj_mfma<<<dim3(16, 8, 4), 256, 0, stream>>>(Et, KVt, partial);
  k_reduce   <<<dim3(512),      256, 0, stream>>>(partial, KVP);
  k_attn     <<<dim3(32, 16),   256, 0, stream>>>(Q, KVP, O);
  k_out      <<<dim3(2, 16, 4), 256, 0, stream>>>(O, W0, out);
}

// Round 5
// 176.288 us; speedup vs baseline: 4.2676x; 1.2914x over previous
//
#include <hip/hip_runtime.h>

// Dims fixed by setup_inputs(): B=4, C=64, H=W=64 -> T=4096, HEADS=8, dh=8, k=T/4=1024
#define T_DIM 4096
#define KD    1024
#define SCALE 0.35355339059327373f   // 8^-0.5
#define LOG2E 1.4426950408889634f

typedef __attribute__((ext_vector_type(8))) short bf16x8;
typedef __attribute__((ext_vector_type(4))) short bf16x4;
typedef __attribute__((ext_vector_type(4))) float f32x4;

__device__ inline unsigned short f2bf(float f) {   // RNE fp32 -> bf16
  unsigned u = __float_as_uint(f);
  unsigned r = u + 0x7fffu + ((u >> 16) & 1u);
  return (unsigned short)(r >> 16);
}

__device__ inline unsigned cvt_pk_bf16(float a, float b) {  // a->lo, b->hi (RNE)
  unsigned ua = __float_as_uint(a); ua += 0x7fffu + ((ua >> 16) & 1u);
  unsigned ub = __float_as_uint(b); ub += 0x7fffu + ((ub >> 16) & 1u);
  return (ua >> 16) | (ub & 0xffff0000u);
}

__device__ inline bf16x4 mk4(unsigned lo, unsigned hi) {
  union { unsigned u[2]; bf16x4 v; } x; x.u[0] = lo; x.u[1] = hi; return x.v;
}

// 16x16x16 bf16 MFMA semantics via the verified 16x16x32 builtin:
// embed each lane's 4 elements (kk = lg*4+j) at j=0..3 of the bf16x8
// (k = lg*8+j); identical embedding on A and B preserves the contraction.
__device__ inline f32x4 mfma16(bf16x4 a, bf16x4 b, f32x4 c) {
  bf16x8 a8 = {}, b8 = {};
  a8[0] = a[0]; a8[1] = a[1]; a8[2] = a[2]; a8[3] = a[3];
  b8[0] = b[0]; b8[1] = b[1]; b8[2] = b[2]; b8[3] = b[3];
  return __builtin_amdgcn_mfma_f32_16x16x32_bf16(a8, b8, c, 0, 0, 0);
}

// ---------------------------------------------------------------------------
// K1: qkv = xf @ Wqkv. Group g = one d (cols [24g,24g+24) share d=g).
//     Q[bh][d][t] fp32; KVt[col][t] bf16 (col=(b*8+h)*16 + sel*8 + d)
// ---------------------------------------------------------------------------
__global__ __launch_bounds__(256) void k_qkv(const float* __restrict__ x,
                                             const float* __restrict__ Wqkv,
                                             float* __restrict__ Q,
                                             unsigned short* __restrict__ KVt) {
  const int g  = blockIdx.x;                 // 0..7 (= d index)
  const int tt = blockIdx.y;                 // 0..15
  const int b  = blockIdx.z;                 // 0..3
  const int t  = tt * 256 + threadIdx.x;
  const int col0 = g * 24;

  float acc[24];
#pragma unroll
  for (int j = 0; j < 24; ++j) acc[j] = 0.f;

  const float* xb = x + (size_t)b * 64 * T_DIM + t;
#pragma unroll 2
  for (int c = 0; c < 64; ++c) {
    float xv = xb[(size_t)c * T_DIM];               // coalesced
    const float* wr = Wqkv + c * 192 + col0;        // wave-uniform -> s_load
#pragma unroll
    for (int j = 0; j < 24; ++j) acc[j] += xv * wr[j];
  }

#pragma unroll
  for (int h = 0; h < 8; ++h)
    Q[(((size_t)(b * 8 + h)) * 8 + g) * T_DIM + t] = acc[h];
#pragma unroll
  for (int h = 0; h < 8; ++h) {
    const int colK = (b * 8 + h) * 16 + g;
    KVt[(size_t)colK * T_DIM + t]       = f2bf(acc[8 + h]);
    KVt[(size_t)(colK + 8) * T_DIM + t] = f2bf(acc[16 + h]);
  }
}

// ---------------------------------------------------------------------------
// K1b: Et = bf16(E^T): E fp32 [4096 t][1024 k] -> Et bf16 [1024 k][4096 t]
// ---------------------------------------------------------------------------
__global__ __launch_bounds__(256) void k_et(const float* __restrict__ E,
                                            unsigned short* __restrict__ Et) {
  __shared__ float Ts[64 * 65];
  const int t0 = blockIdx.x * 64;
  const int k0 = blockIdx.y * 64;
  const int tid = threadIdx.x;

  const int c = tid & 63;
#pragma unroll
  for (int ii = 0; ii < 16; ++ii) {
    const int r = (tid >> 6) * 16 + ii;
    Ts[c * 65 + r] = E[(size_t)(t0 + r) * KD + k0 + c];
  }
  __syncthreads();

  const int p = tid & 31;
#pragma unroll
  for (int ii = 0; ii < 8; ++ii) {
    const int kk = (tid >> 5) * 8 + ii;
    unsigned v = cvt_pk_bf16(Ts[kk * 65 + 2 * p], Ts[kk * 65 + 2 * p + 1]);
    *(unsigned*)(Et + (size_t)(k0 + kk) * T_DIM + t0 + 2 * p) = v;
  }
}

// ---------------------------------------------------------------------------
// K2: MFMA GEMM: partial[s][m][n] = sum_t Et[m][t] * KVt[n][t]
// ---------------------------------------------------------------------------
__global__ __launch_bounds__(256) void k_proj_mfma(const unsigned short* __restrict__ Et,
                                                   const unsigned short* __restrict__ KVt,
                                                   float* __restrict__ partial) {
  __shared__ unsigned short As[64 * 72];
  __shared__ unsigned short Bs[64 * 72];
  const int m0 = blockIdx.x * 64;
  const int n0 = blockIdx.y * 64;
  const int s  = blockIdx.z;
  const int tid = threadIdx.x;
  const int lane = tid & 63;
  const int w = tid >> 6;
  const int mw = (w & 1) * 32, nw = (w >> 1) * 32;

  f32x4 acc[2][2] = {};
  const int r0 = tid >> 3, o0 = tid & 7;

  for (int tb = 0; tb < 1024; tb += 64) {
    const int tbase = s * 1024 + tb;
    bf16x8 va  = *(const bf16x8*)(Et  + (size_t)(m0 + r0)      * T_DIM + tbase + o0 * 8);
    bf16x8 va2 = *(const bf16x8*)(Et  + (size_t)(m0 + r0 + 32) * T_DIM + tbase + o0 * 8);
    bf16x8 vb  = *(const bf16x8*)(KVt + (size_t)(n0 + r0)      * T_DIM + tbase + o0 * 8);
    bf16x8 vb2 = *(const bf16x8*)(KVt + (size_t)(n0 + r0 + 32) * T_DIM + tbase + o0 * 8);
    __syncthreads();
    *(bf16x8*)(As + r0 * 72 + o0 * 8)        = va;
    *(bf16x8*)(As + (r0 + 32) * 72 + o0 * 8) = va2;
    *(bf16x8*)(Bs + r0 * 72 + o0 * 8)        = vb;
    *(bf16x8*)(Bs + (r0 + 32) * 72 + o0 * 8) = vb2;
    __syncthreads();

#pragma unroll
    for (int ks = 0; ks < 2; ++ks) {
      const int ko = ks * 32 + (lane >> 4) * 8;
      bf16x8 a0 = *(const bf16x8*)(As + (mw +      (lane & 15)) * 72 + ko);
      bf16x8 a1 = *(const bf16x8*)(As + (mw + 16 + (lane & 15)) * 72 + ko);
      bf16x8 b0 = *(const bf16x8*)(Bs + (nw +      (lane & 15)) * 72 + ko);
      bf16x8 b1 = *(const bf16x8*)(Bs + (nw + 16 + (lane & 15)) * 72 + ko);
      acc[0][0] = __builtin_amdgcn_mfma_f32_16x16x32_bf16(a0, b0, acc[0][0], 0, 0, 0);
      acc[0][1] = __builtin_amdgcn_mfma_f32_16x16x32_bf16(a0, b1, acc[0][1], 0, 0, 0);
      acc[1][0] = __builtin_amdgcn_mfma_f32_16x16x32_bf16(a1, b0, acc[1][0], 0, 0, 0);
      acc[1][1] = __builtin_amdgcn_mfma_f32_16x16x32_bf16(a1, b1, acc[1][1], 0, 0, 0);
    }
  }

  float* pb = partial + (size_t)s * (KD * 512);
#pragma unroll
  for (int rr = 0; rr < 2; ++rr)
#pragma unroll
    for (int cc = 0; cc < 2; ++cc) {
      const int mrow = m0 + mw + rr * 16 + (lane >> 4) * 4;
      const int ncol = n0 + nw + cc * 16 + (lane & 15);
#pragma unroll
      for (int reg = 0; reg < 4; ++reg)
        pb[(size_t)(mrow + reg) * 512 + ncol] = acc[rr][cc][reg];
    }
}

// ---------------------------------------------------------------------------
// K2b: KVP[bh][k][16] = sum_s partial[s][k][bh*16+ch]
// ---------------------------------------------------------------------------
__global__ __launch_bounds__(256) void k_reduce(const float* __restrict__ partial,
                                                float* __restrict__ KVP) {
  const size_t o = ((size_t)blockIdx.x * 256 + threadIdx.x) * 4;
  const int ch0 = (int)(o & 15);
  const int k   = (int)((o >> 4) & 1023);
  const int bh  = (int)(o >> 14);
  const size_t src = (size_t)k * 512 + bh * 16 + ch0;
  float4 a = make_float4(0.f, 0.f, 0.f, 0.f);
#pragma unroll
  for (int s = 0; s < 4; ++s) {
    float4 v = *(const float4*)(partial + (size_t)s * (KD * 512) + src);
    a.x += v.x; a.y += v.y; a.z += v.z; a.w += v.w;
  }
  *(float4*)(KVP + o) = a;
}

// ---------------------------------------------------------------------------
// K3: MFMA flash attention. S^T = K'.Q^T; its C/D frag is bit-identical to
//     the B-operand frag of the PV mfma (16x16x16 layout embedded in the
//     x32 instruction), so exp2(S^T) feeds PV with no data movement.
//     Ones-row (d=8) in V'' yields the softmax denominator from the same
//     PV accumulator.
// ---------------------------------------------------------------------------
#define VT_PITCH 1032
__global__ __launch_bounds__(256) void k_attn(const float* __restrict__ Q,
                                              const float* __restrict__ KVP,
                                              float* __restrict__ O) {
  __shared__ unsigned short Kt[2 * 1024 * 4];   // [g][j][4] bf16, g = d-quad, prescaled
  __shared__ unsigned short Vt[9 * VT_PITCH];   // [d][j] bf16, row 8 = ones
  const int bh = blockIdx.x;
  const int tid = threadIdx.x;
  const float ks = SCALE * LOG2E;

  // stage K' (scaled by SCALE*log2e) and V'' from KVP
#pragma unroll
  for (int it = 0; it < 4; ++it) {
    const int j = it * 256 + tid;
    const float* row = KVP + ((size_t)bh * 1024 + j) * 16;
    float4 k0 = *(const float4*)(row);
    float4 k1 = *(const float4*)(row + 4);
    float4 v0 = *(const float4*)(row + 8);
    float4 v1 = *(const float4*)(row + 12);
    unsigned a0 = cvt_pk_bf16(k0.x * ks, k0.y * ks);
    unsigned a1 = cvt_pk_bf16(k0.z * ks, k0.w * ks);
    unsigned a2 = cvt_pk_bf16(k1.x * ks, k1.y * ks);
    unsigned a3 = cvt_pk_bf16(k1.z * ks, k1.w * ks);
    *(uint2*)(&Kt[(size_t)j * 4])          = make_uint2(a0, a1);
    *(uint2*)(&Kt[(size_t)(1024 + j) * 4]) = make_uint2(a2, a3);
    unsigned b0 = cvt_pk_bf16(v0.x, v0.y);
    unsigned b1 = cvt_pk_bf16(v0.z, v0.w);
    unsigned b2 = cvt_pk_bf16(v1.x, v1.y);
    unsigned b3 = cvt_pk_bf16(v1.z, v1.w);
    Vt[0 * VT_PITCH + j] = (unsigned short)b0;
    Vt[1 * VT_PITCH + j] = (unsigned short)(b0 >> 16);
    Vt[2 * VT_PITCH + j] = (unsigned short)b1;
    Vt[3 * VT_PITCH + j] = (unsigned short)(b1 >> 16);
    Vt[4 * VT_PITCH + j] = (unsigned short)b2;
    Vt[5 * VT_PITCH + j] = (unsigned short)(b2 >> 16);
    Vt[6 * VT_PITCH + j] = (unsigned short)b3;
    Vt[7 * VT_PITCH + j] = (unsigned short)(b3 >> 16);
    Vt[8 * VT_PITCH + j] = 0x3F80;                      // 1.0
  }
  __syncthreads();

  const int lane = tid & 63, w = tid >> 6;
  const int li = lane & 15, lg = lane >> 4;             // lg 0..3
  const int i0w = blockIdx.y * 128 + w * 32;

  // Q fragments (B-operand): lane(i=li, d=lg*4+j'), lanes>=32 zero-pad d 8..15
  bf16x4 qf[2] = {bf16x4{}, bf16x4{}};
  if (lane < 32) {
#pragma unroll
    for (int it2 = 0; it2 < 2; ++it2) {
      const float* qp = Q + ((size_t)bh * 8 + lg * 4) * T_DIM + i0w + it2 * 16 + li;
      qf[it2] = mk4(cvt_pk_bf16(qp[0], qp[T_DIM]),
                    cvt_pk_bf16(qp[2 * T_DIM], qp[3 * T_DIM]));
    }
  }

  f32x4 accO[2] = {f32x4{0.f, 0.f, 0.f, 0.f}, f32x4{0.f, 0.f, 0.f, 0.f}};
#pragma unroll 2
  for (int jt = 0; jt < 1024; jt += 16) {
    bf16x4 kf = {};
    if (lane < 32) kf = *(const bf16x4*)(&Kt[(size_t)(lg * 1024 + jt + li) * 4]);
    bf16x4 vf = {};
    if (li < 9) vf = *(const bf16x4*)(&Vt[li * VT_PITCH + jt + lg * 4]);
#pragma unroll
    for (int it2 = 0; it2 < 2; ++it2) {
      f32x4 st = mfma16(kf, qf[it2], f32x4{0.f, 0.f, 0.f, 0.f});  // S^T tile
      f32x4 p;
      p[0] = exp2f(st[0]); p[1] = exp2f(st[1]);
      p[2] = exp2f(st[2]); p[3] = exp2f(st[3]);
      bf16x4 pf = mk4(cvt_pk_bf16(p[0], p[1]), cvt_pk_bf16(p[2], p[3]));
      accO[it2] = mfma16(vf, pf, accO[it2]);                      // O^T += V''.P
    }
  }

  const int b = bh >> 3, h = bh & 7;
#pragma unroll
  for (int it2 = 0; it2 < 2; ++it2) {
    float l = __shfl(accO[it2][0], 32 + li);    // D[8][i] = sum_j p  (ones row)
    float inv = 1.0f / l;
    if (lane < 32) {
      const int i = i0w + it2 * 16 + li;
      float4 o = make_float4(accO[it2][0] * inv, accO[it2][1] * inv,
                             accO[it2][2] * inv, accO[it2][3] * inv);
      *(float4*)(O + ((size_t)b * T_DIM + i) * 64 + h * 8 + lg * 4) = o;
    }
  }
}

// ---------------------------------------------------------------------------
// K4: out[b][c][t] = (O[b][t][:] @ W0)[c]  — 8 cols/thread, 512 blocks
// ---------------------------------------------------------------------------
__global__ __launch_bounds__(256) void k_out(const float* __restrict__ O,
                                             const float* __restrict__ W0,
                                             float* __restrict__ out) {
  const int cg = blockIdx.x;                 // 0..7
  const int tt = blockIdx.y;                 // 0..15
  const int b  = blockIdx.z;                 // 0..3
  const int t  = tt * 256 + threadIdx.x;
  const int col0 = cg * 8;

  float acc[8];
#pragma unroll
  for (int j = 0; j < 8; ++j) acc[j] = 0.f;

  const float* orow = O + ((size_t)b * T_DIM + t) * 64;
#pragma unroll
  for (int c0 = 0; c0 < 64; c0 += 4) {
    float4 v = *(const float4*)(orow + c0);
    float ov[4] = {v.x, v.y, v.z, v.w};
#pragma unroll
    for (int u = 0; u < 4; ++u) {
      const float* wr = W0 + (c0 + u) * 64 + col0;   // uniform -> s_load
#pragma unroll
      for (int j = 0; j < 8; ++j) acc[j] += ov[u] * wr[j];
    }
  }
#pragma unroll
  for (int j = 0; j < 8; ++j)
    out[((size_t)b * 64 + col0 + j) * T_DIM + t] = acc[j];   // coalesced
}

// ---------------------------------------------------------------------------
extern "C" void kernel_launch(void* const* d_in, const int* in_sizes, int n_in,
                              void* d_out, int out_size, void* d_ws, size_t ws_size,
                              hipStream_t stream) {
  const float* x    = (const float*)d_in[0];
  // d_in[1..4] = conv_w, conv_b, ln_g, ln_b : dead code in the reference
  const float* Wqkv = (const float*)d_in[5];
  const float* W0   = (const float*)d_in[6];
  const float* E    = (const float*)d_in[7];
  float* out = (float*)d_out;

  // workspace layout (30 MB total)
  float* Q       = (float*)d_ws;                    // 1,048,576 f (4 MB)
  float* O       = Q + 1048576;                     // 1,048,576 f (4 MB)
  float* KVP     = O + 1048576;                     //   524,288 f (2 MB)
  float* partial = KVP + 524288;                    // 2,097,152 f (8 MB)
  unsigned short* KVt = (unsigned short*)(partial + 2097152);  // 4 MB
  unsigned short* Et  = KVt + 2097152;              // 8 MB

  k_qkv      <<<dim3(8, 16, 4), 256, 0, stream>>>(x, Wqkv, Q, KVt);
  k_et       <<<dim3(64, 16),   256, 0, stream>>>(E, Et);
  k_proj_mfma<<<dim3(16, 8, 4), 256, 0, stream>>>(Et, KVt, partial);
  k_reduce   <<<dim3(512),      256, 0, stream>>>(partial, KVP);
  k_attn     <<<dim3(32, 32),   256, 0, stream>>>(Q, KVP, O);
  k_out      <<<dim3(8, 16, 4), 256, 0, stream>>>(O, W0, out);
}

// Round 6
// 167.897 us; speedup vs baseline: 4.4809x; 1.0500x over previous
//
#include <hip/hip_runtime.h>

// Dims fixed by setup_inputs(): B=4, C=64, H=W=64 -> T=4096, HEADS=8, dh=8, k=T/4=1024
#define T_DIM 4096
#define KD    1024
#define SCALE 0.35355339059327373f   // 8^-0.5

typedef __attribute__((ext_vector_type(8))) short bf16x8;
typedef __attribute__((ext_vector_type(4))) short bf16x4;
typedef __attribute__((ext_vector_type(4))) float f32x4;

__device__ inline unsigned cvt_pk_bf16(float a, float b) {  // a->lo, b->hi (RNE)
  unsigned ua = __float_as_uint(a); ua += 0x7fffu + ((ua >> 16) & 1u);
  unsigned ub = __float_as_uint(b); ub += 0x7fffu + ((ub >> 16) & 1u);
  return (ua >> 16) | (ub & 0xffff0000u);
}

__device__ inline bf16x4 mk4(unsigned lo, unsigned hi) {
  union { unsigned u[2]; bf16x4 v; } x; x.u[0] = lo; x.u[1] = hi; return x.v;
}

__device__ inline bf16x8 mk8(unsigned a, unsigned b, unsigned c, unsigned d) {
  union { unsigned u[4]; bf16x8 v; } x;
  x.u[0] = a; x.u[1] = b; x.u[2] = c; x.u[3] = d; return x.v;
}

// 16x16x16 bf16 MFMA semantics via the verified 16x16x32 builtin (j=4..7 zero).
__device__ inline f32x4 mfma16(bf16x4 a, bf16x4 b, f32x4 c) {
  bf16x8 a8 = {}, b8 = {};
  a8[0] = a[0]; a8[1] = a[1]; a8[2] = a[2]; a8[3] = a[3];
  b8[0] = b[0]; b8[1] = b[1]; b8[2] = b[2]; b8[3] = b[3];
  return __builtin_amdgcn_mfma_f32_16x16x32_bf16(a8, b8, c, 0, 0, 0);
}

// ---------------------------------------------------------------------------
// K1: Q = xf @ Wq only (cols d*24 + h).  Q[bh][d][t] fp32, coalesced in t.
// ---------------------------------------------------------------------------
__global__ __launch_bounds__(256) void k_q(const float* __restrict__ x,
                                           const float* __restrict__ Wqkv,
                                           float* __restrict__ Q) {
  const int g  = blockIdx.x;                 // 0..7 (= d index)
  const int tt = blockIdx.y;                 // 0..15
  const int b  = blockIdx.z;                 // 0..3
  const int t  = tt * 256 + threadIdx.x;
  const int col0 = g * 24;                   // k3=0 (Q) cols: col0 + h

  float acc[8];
#pragma unroll
  for (int j = 0; j < 8; ++j) acc[j] = 0.f;

  const float* xb = x + (size_t)b * 64 * T_DIM + t;
#pragma unroll 4
  for (int c = 0; c < 64; ++c) {
    float xv = xb[(size_t)c * T_DIM];               // coalesced
    const float* wr = Wqkv + c * 192 + col0;        // wave-uniform -> s_load
#pragma unroll
    for (int h = 0; h < 8; ++h) acc[h] += xv * wr[h];
  }
#pragma unroll
  for (int h = 0; h < 8; ++h)
    Q[(((size_t)(b * 8 + h)) * 8 + g) * T_DIM + t] = acc[h];
}

// ---------------------------------------------------------------------------
// K2: XP partials = x[b] @ E   (M=64 c, N=1024 k, K=4096 t, 16-way K-split)
//     A (x, t-contig) staged in LDS as bf16; B (E) fragments loaded directly
//     from global (lanes span 16 consecutive k -> coalesced) and packed.
//     partial[s*4+b][c][k] fp32.
// ---------------------------------------------------------------------------
__global__ __launch_bounds__(256) void k_xe(const float* __restrict__ x,
                                            const float* __restrict__ E,
                                            float* __restrict__ partial) {
  __shared__ unsigned short As[64 * 72];     // [c][t] bf16, pitch 72
  const int kb = blockIdx.x;                 // 0..7  -> k0 = kb*128
  const int b  = blockIdx.y;                 // 0..3
  const int s  = blockIdx.z;                 // 0..15 -> t-range s*256
  const int k0 = kb * 128;
  const int tid = threadIdx.x;
  const int lane = tid & 63;
  const int w = tid >> 6;                    // wave: n-range w*32
  const int li = lane & 15, lg = lane >> 4;

  f32x4 acc[4][2] = {};                      // [mt][nt]

  const int ar = tid >> 4;                   // staging row subset (16 rows/pass)
  const int af = tid & 15;                   // float4 index within row

  for (int tb = 0; tb < 4; ++tb) {
    const int t0 = s * 256 + tb * 64;
    // ---- stage A: x[b][0:64][t0:t0+64] -> As (bf16) ----
    float4 av[4];
#pragma unroll
    for (int ii = 0; ii < 4; ++ii)
      av[ii] = *(const float4*)(x + ((size_t)b * 64 + ar + ii * 16) * T_DIM + t0 + af * 4);
    __syncthreads();                         // previous-iter reads done
#pragma unroll
    for (int ii = 0; ii < 4; ++ii) {
      unsigned lo = cvt_pk_bf16(av[ii].x, av[ii].y);
      unsigned hi = cvt_pk_bf16(av[ii].z, av[ii].w);
      *(uint2*)(As + (ar + ii * 16) * 72 + af * 4) = make_uint2(lo, hi);
    }
    __syncthreads();

#pragma unroll
    for (int ks = 0; ks < 2; ++ks) {
      const int tbase = t0 + ks * 32 + lg * 8;
      // B fragments: E[tbase+j][k0 + w*32 + nt*16 + li], j=0..7
      bf16x8 bq[2];
#pragma unroll
      for (int nt = 0; nt < 2; ++nt) {
        const int kcol = k0 + w * 32 + nt * 16 + li;
        float bv[8];
#pragma unroll
        for (int j = 0; j < 8; ++j)
          bv[j] = E[(size_t)(tbase + j) * KD + kcol];
        bq[nt] = mk8(cvt_pk_bf16(bv[0], bv[1]), cvt_pk_bf16(bv[2], bv[3]),
                     cvt_pk_bf16(bv[4], bv[5]), cvt_pk_bf16(bv[6], bv[7]));
      }
#pragma unroll
      for (int mt = 0; mt < 4; ++mt) {
        bf16x8 af8 = *(const bf16x8*)(As + (mt * 16 + li) * 72 + ks * 32 + lg * 8);
#pragma unroll
        for (int nt = 0; nt < 2; ++nt)
          acc[mt][nt] = __builtin_amdgcn_mfma_f32_16x16x32_bf16(af8, bq[nt], acc[mt][nt], 0, 0, 0);
      }
    }
  }

  // C/D layout: col = lane&15, row = (lane>>4)*4 + reg  [verified m89]
  float* pb = partial + ((size_t)s * 4 + b) * (64 * KD);
#pragma unroll
  for (int mt = 0; mt < 4; ++mt)
#pragma unroll
    for (int nt = 0; nt < 2; ++nt) {
      const int row = mt * 16 + lg * 4;
      const int col = k0 + w * 32 + nt * 16 + li;
#pragma unroll
      for (int reg = 0; reg < 4; ++reg)
        pb[(size_t)(row + reg) * KD + col] = acc[mt][nt][reg];
    }
}

// ---------------------------------------------------------------------------
// K2b: XP[b][c][k] (bf16) = sum_s partial[s][b][c][k]
// ---------------------------------------------------------------------------
__global__ __launch_bounds__(256) void k_xered(const float* __restrict__ partial,
                                               unsigned short* __restrict__ XP) {
  const size_t o = ((size_t)blockIdx.x * 256 + threadIdx.x) * 4;  // 262144 elems
  const int k4 = (int)(o & 1023);
  const int cb = (int)(o >> 10);             // b*64 + c
  const size_t src = (size_t)cb * KD + k4;
  float4 a = make_float4(0.f, 0.f, 0.f, 0.f);
#pragma unroll
  for (int s = 0; s < 16; ++s) {
    float4 v = *(const float4*)(partial + ((size_t)s * 4) * (64 * KD) + src);
    a.x += v.x; a.y += v.y; a.z += v.z; a.w += v.w;
  }
  // note: partial is [s][b][c][k]; fold b into cb by striding s*4 blocks
  *(uint2*)(XP + o) = make_uint2(cvt_pk_bf16(a.x, a.y), cvt_pk_bf16(a.z, a.w));
}

// ---------------------------------------------------------------------------
// K2c: KVP[bh][k][16] = XP^T @ Wkv   (ch 0..7 = K-d, 8..15 = V-d)
//      wcol(d) = d*24 + (sel+1)*8 + h
// ---------------------------------------------------------------------------
__global__ __launch_bounds__(256) void k_kvp(const unsigned short* __restrict__ XP,
                                             const float* __restrict__ Wqkv,
                                             float* __restrict__ KVP) {
  const int kb  = blockIdx.x >> 1;           // 0..3
  const int sel = blockIdx.x & 1;            // 0=K, 1=V
  const int h   = blockIdx.y;                // 0..7
  const int b   = blockIdx.z;                // 0..3
  const int k   = kb * 256 + threadIdx.x;

  float acc[8];
#pragma unroll
  for (int d = 0; d < 8; ++d) acc[d] = 0.f;

  const unsigned short* xb = XP + (size_t)b * 64 * KD + k;
#pragma unroll 4
  for (int c = 0; c < 64; ++c) {
    float xv = __uint_as_float((unsigned)xb[(size_t)c * KD] << 16);  // coalesced
    const float* wr = Wqkv + c * 192 + (sel + 1) * 8 + h;            // s_load
#pragma unroll
    for (int d = 0; d < 8; ++d) acc[d] += xv * wr[d * 24];
  }

  float* op = KVP + (((size_t)(b * 8 + h)) * KD + k) * 16 + sel * 8;
  *(float4*)(op)     = make_float4(acc[0], acc[1], acc[2], acc[3]);
  *(float4*)(op + 4) = make_float4(acc[4], acc[5], acc[6], acc[7]);
}

// ---------------------------------------------------------------------------
// K3: MFMA flash attention (S^T chain identity; ones-row denominator).
//     __expf (native v_exp_f32), K' prescaled by SCALE only.
// ---------------------------------------------------------------------------
#define VT_PITCH 1032
__global__ __launch_bounds__(256) void k_attn(const float* __restrict__ Q,
                                              const float* __restrict__ KVP,
                                              float* __restrict__ O) {
  __shared__ unsigned short Kt[2 * 1024 * 4];   // [g][j][4] bf16, prescaled
  __shared__ unsigned short Vt[9 * VT_PITCH];   // [d][j] bf16, row 8 = ones
  const int bh = blockIdx.x;
  const int tid = threadIdx.x;
  const float ks = SCALE;

#pragma unroll
  for (int it = 0; it < 4; ++it) {
    const int j = it * 256 + tid;
    const float* row = KVP + ((size_t)bh * 1024 + j) * 16;
    float4 k0 = *(const float4*)(row);
    float4 k1 = *(const float4*)(row + 4);
    float4 v0 = *(const float4*)(row + 8);
    float4 v1 = *(const float4*)(row + 12);
    unsigned a0 = cvt_pk_bf16(k0.x * ks, k0.y * ks);
    unsigned a1 = cvt_pk_bf16(k0.z * ks, k0.w * ks);
    unsigned a2 = cvt_pk_bf16(k1.x * ks, k1.y * ks);
    unsigned a3 = cvt_pk_bf16(k1.z * ks, k1.w * ks);
    *(uint2*)(&Kt[(size_t)j * 4])          = make_uint2(a0, a1);
    *(uint2*)(&Kt[(size_t)(1024 + j) * 4]) = make_uint2(a2, a3);
    unsigned b0 = cvt_pk_bf16(v0.x, v0.y);
    unsigned b1 = cvt_pk_bf16(v0.z, v0.w);
    unsigned b2 = cvt_pk_bf16(v1.x, v1.y);
    unsigned b3 = cvt_pk_bf16(v1.z, v1.w);
    Vt[0 * VT_PITCH + j] = (unsigned short)b0;
    Vt[1 * VT_PITCH + j] = (unsigned short)(b0 >> 16);
    Vt[2 * VT_PITCH + j] = (unsigned short)b1;
    Vt[3 * VT_PITCH + j] = (unsigned short)(b1 >> 16);
    Vt[4 * VT_PITCH + j] = (unsigned short)b2;
    Vt[5 * VT_PITCH + j] = (unsigned short)(b2 >> 16);
    Vt[6 * VT_PITCH + j] = (unsigned short)b3;
    Vt[7 * VT_PITCH + j] = (unsigned short)(b3 >> 16);
    Vt[8 * VT_PITCH + j] = 0x3F80;                      // 1.0
  }
  __syncthreads();

  const int lane = tid & 63, w = tid >> 6;
  const int li = lane & 15, lg = lane >> 4;
  const int i0w = blockIdx.y * 128 + w * 32;

  bf16x4 qf[2] = {bf16x4{}, bf16x4{}};
  if (lane < 32) {
#pragma unroll
    for (int it2 = 0; it2 < 2; ++it2) {
      const float* qp = Q + ((size_t)bh * 8 + lg * 4) * T_DIM + i0w + it2 * 16 + li;
      qf[it2] = mk4(cvt_pk_bf16(qp[0], qp[T_DIM]),
                    cvt_pk_bf16(qp[2 * T_DIM], qp[3 * T_DIM]));
    }
  }

  f32x4 accO[2] = {f32x4{0.f, 0.f, 0.f, 0.f}, f32x4{0.f, 0.f, 0.f, 0.f}};
#pragma unroll 2
  for (int jt = 0; jt < 1024; jt += 16) {
    bf16x4 kf = {};
    if (lane < 32) kf = *(const bf16x4*)(&Kt[(size_t)(lg * 1024 + jt + li) * 4]);
    bf16x4 vf = {};
    if (li < 9) vf = *(const bf16x4*)(&Vt[li * VT_PITCH + jt + lg * 4]);
#pragma unroll
    for (int it2 = 0; it2 < 2; ++it2) {
      f32x4 st = mfma16(kf, qf[it2], f32x4{0.f, 0.f, 0.f, 0.f});  // S^T tile
      f32x4 p;
      p[0] = __expf(st[0]); p[1] = __expf(st[1]);
      p[2] = __expf(st[2]); p[3] = __expf(st[3]);
      bf16x4 pf = mk4(cvt_pk_bf16(p[0], p[1]), cvt_pk_bf16(p[2], p[3]));
      accO[it2] = mfma16(vf, pf, accO[it2]);                      // O^T += V''.P
    }
  }

  const int b = bh >> 3, h = bh & 7;
#pragma unroll
  for (int it2 = 0; it2 < 2; ++it2) {
    float l = __shfl(accO[it2][0], 32 + li);    // denominator (ones row)
    float inv = 1.0f / l;
    if (lane < 32) {
      const int i = i0w + it2 * 16 + li;
      float4 o = make_float4(accO[it2][0] * inv, accO[it2][1] * inv,
                             accO[it2][2] * inv, accO[it2][3] * inv);
      *(float4*)(O + ((size_t)b * T_DIM + i) * 64 + h * 8 + lg * 4) = o;
    }
  }
}

// ---------------------------------------------------------------------------
// K4: out[b][c][t] = (O[b][t][:] @ W0)[c]
// ---------------------------------------------------------------------------
__global__ __launch_bounds__(256) void k_out(const float* __restrict__ O,
                                             const float* __restrict__ W0,
                                             float* __restrict__ out) {
  const int cg = blockIdx.x;                 // 0..7
  const int tt = blockIdx.y;                 // 0..15
  const int b  = blockIdx.z;                 // 0..3
  const int t  = tt * 256 + threadIdx.x;
  const int col0 = cg * 8;

  float acc[8];
#pragma unroll
  for (int j = 0; j < 8; ++j) acc[j] = 0.f;

  const float* orow = O + ((size_t)b * T_DIM + t) * 64;
#pragma unroll
  for (int c0 = 0; c0 < 64; c0 += 4) {
    float4 v = *(const float4*)(orow + c0);
    float ov[4] = {v.x, v.y, v.z, v.w};
#pragma unroll
    for (int u = 0; u < 4; ++u) {
      const float* wr = W0 + (c0 + u) * 64 + col0;   // uniform -> s_load
#pragma unroll
      for (int j = 0; j < 8; ++j) acc[j] += ov[u] * wr[j];
    }
  }
#pragma unroll
  for (int j = 0; j < 8; ++j)
    out[((size_t)b * 64 + col0 + j) * T_DIM + t] = acc[j];   // coalesced
}

// ---------------------------------------------------------------------------
extern "C" void kernel_launch(void* const* d_in, const int* in_sizes, int n_in,
                              void* d_out, int out_size, void* d_ws, size_t ws_size,
                              hipStream_t stream) {
  const float* x    = (const float*)d_in[0];
  // d_in[1..4] = conv_w, conv_b, ln_g, ln_b : dead code in the reference
  const float* Wqkv = (const float*)d_in[5];
  const float* W0   = (const float*)d_in[6];
  const float* E    = (const float*)d_in[7];
  float* out = (float*)d_out;

  // workspace layout (~26.5 MB)
  float* Q       = (float*)d_ws;                    // 1,048,576 f (4 MB)
  float* O       = Q + 1048576;                     // 1,048,576 f (4 MB)
  float* KVP     = O + 1048576;                     //   524,288 f (2 MB)
  float* partial = KVP + 524288;                    // 4,194,304 f (16 MB)
  unsigned short* XP = (unsigned short*)(partial + 4194304);   // 262,144 bf16 (0.5 MB)

  k_q     <<<dim3(8, 16, 4), 256, 0, stream>>>(x, Wqkv, Q);
  k_xe    <<<dim3(8, 4, 16), 256, 0, stream>>>(x, E, partial);
  k_xered <<<dim3(256),      256, 0, stream>>>(partial + (size_t)0, XP);   // note below
  k_kvp   <<<dim3(8, 8, 4),  256, 0, stream>>>(XP, Wqkv, KVP);
  k_attn  <<<dim3(32, 32),   256, 0, stream>>>(Q, KVP, O);
  k_out   <<<dim3(8, 16, 4), 256, 0, stream>>>(O, W0, out);
}